// Round 1
// baseline (460.639 us; speedup 1.0000x reference)
//
#include <hip/hip_runtime.h>

// EUNN: 256 layers; each layer = rotation on even pairs (2i,2i+1), then
// rotation on odd pairs (2i+1,2i+2 mod H) (the roll(-1)/roll(+1) sandwich).
// Pair math: y0 = e^{i*phi} (ct*u - st*v); y1 = st*u + ct*v.

#define BS 4096
#define H_DIM 1024
#define H2 512
#define C2 256
#define RPW 4   // batch rows per wave

// coef layout: [c][phase][j][lane] as float4 (ct, st, cp, sp), pair i = 8*lane + j
// -> flat float4 index: ((c*2 + phase)*8 + j)*64 + lane,  4 MB total.

__global__ __launch_bounds__(256) void eunn_coef_kernel(
    const float* __restrict__ phi0, const float* __restrict__ theta0,
    const float* __restrict__ phi1, const float* __restrict__ theta1,
    float4* __restrict__ coef) {
    int t = blockIdx.x * 256 + threadIdx.x;     // [0, 256*2*512)
    int i = t & 511;                            // pair index
    int p = (t >> 9) & 1;                       // phase (0: even pairs, 1: odd pairs)
    int c = t >> 10;                            // layer
    const float* phi   = p ? phi1   : phi0;
    const float* theta = p ? theta1 : theta0;
    float ph = phi[i * C2 + c];
    float th = theta[i * C2 + c];
    float sp, cp, st, ct;
    sincosf(ph, &sp, &cp);
    sincosf(th, &st, &ct);
    int j = i & 7;
    int l = i >> 3;
    coef[(((c * 2 + p) * 8) + j) * 64 + l] = make_float4(ct, st, cp, sp);
}

__device__ __forceinline__ void rot_pair(const float4 q,
                                         float& ur, float& ui,
                                         float& wr, float& wi) {
    // q = (ct, st, cp, sp)
    float ar = fmaf(-q.y, wr, q.x * ur);   // ct*u - st*v (real)
    float ai = fmaf(-q.y, wi, q.x * ui);
    float br = fmaf( q.x, wr, q.y * ur);   // st*u + ct*v (real)
    float bi = fmaf( q.x, wi, q.y * ui);
    ur = fmaf(-q.w, ai, q.z * ar);         // e^{i phi} * a
    ui = fmaf( q.w, ar, q.z * ai);
    wr = br;
    wi = bi;
}

__global__ __launch_bounds__(256, 2) void eunn_main_kernel(
    const float* __restrict__ x,
    const float4* __restrict__ coef,
    float* __restrict__ out) {
    const int lane = threadIdx.x & 63;
    const int wave = threadIdx.x >> 6;
    const int row0 = (blockIdx.x * 4 + wave) * RPW;

    // lane owns complex elements [16*lane, 16*lane+16) of each of its RPW rows
    float vr[RPW][16], vi[RPW][16];

#pragma unroll
    for (int r = 0; r < RPW; ++r) {
        const float4* src = (const float4*)(x + (size_t)(row0 + r) * (H_DIM * 2)) + lane * 8;
#pragma unroll
        for (int m = 0; m < 8; ++m) {
            float4 f = src[m];
            vr[r][2 * m]     = f.x; vi[r][2 * m]     = f.y;
            vr[r][2 * m + 1] = f.z; vi[r][2 * m + 1] = f.w;
        }
    }

#pragma unroll 1
    for (int c = 0; c < C2; ++c) {
        const float4* ca = coef + (size_t)c * 1024;

        // phase A: pairs (2i, 2i+1), local (2j, 2j+1)
#pragma unroll
        for (int j = 0; j < 8; ++j) {
            float4 q = ca[j * 64 + lane];
#pragma unroll
            for (int r = 0; r < RPW; ++r) {
                rot_pair(q, vr[r][2 * j], vi[r][2 * j],
                            vr[r][2 * j + 1], vi[r][2 * j + 1]);
            }
        }

        // phase B internal: pairs (2i+1, 2i+2), local (2j+1, 2j+2), j=0..6
#pragma unroll
        for (int j = 0; j < 7; ++j) {
            float4 q = ca[(8 + j) * 64 + lane];
#pragma unroll
            for (int r = 0; r < RPW; ++r) {
                rot_pair(q, vr[r][2 * j + 1], vi[r][2 * j + 1],
                            vr[r][2 * j + 2], vi[r][2 * j + 2]);
            }
        }

        // phase B boundary: pair (local 15 of lane, local 0 of lane+1), wraps 63->0
        {
            float4 q = ca[15 * 64 + lane];
#pragma unroll
            for (int r = 0; r < RPW; ++r) {
                float nwr = __shfl(vr[r][0], (lane + 1) & 63);
                float nwi = __shfl(vi[r][0], (lane + 1) & 63);
                rot_pair(q, vr[r][15], vi[r][15], nwr, nwi);
                vr[r][0] = __shfl(nwr, (lane + 63) & 63);
                vi[r][0] = __shfl(nwi, (lane + 63) & 63);
            }
        }
    }

#pragma unroll
    for (int r = 0; r < RPW; ++r) {
        float4* dst = (float4*)(out + (size_t)(row0 + r) * (H_DIM * 2)) + lane * 8;
#pragma unroll
        for (int m = 0; m < 8; ++m) {
            dst[m] = make_float4(vr[r][2 * m],     vi[r][2 * m],
                                 vr[r][2 * m + 1], vi[r][2 * m + 1]);
        }
    }
}

extern "C" void kernel_launch(void* const* d_in, const int* in_sizes, int n_in,
                              void* d_out, int out_size, void* d_ws, size_t ws_size,
                              hipStream_t stream) {
    const float* x      = (const float*)d_in[0];
    const float* phi0   = (const float*)d_in[1];
    const float* theta0 = (const float*)d_in[2];
    const float* phi1   = (const float*)d_in[3];
    const float* theta1 = (const float*)d_in[4];
    float* out = (float*)d_out;
    float4* coef = (float4*)d_ws;   // 256*1024 float4 = 4 MB

    // coefficients: 256 layers * 2 phases * 512 pairs = 262144 threads
    hipLaunchKernelGGL(eunn_coef_kernel, dim3(1024), dim3(256), 0, stream,
                       phi0, theta0, phi1, theta1, coef);

    // main: 4096 rows / (4 waves * RPW rows) = 256 blocks
    hipLaunchKernelGGL(eunn_main_kernel, dim3(256), dim3(256), 0, stream,
                       x, coef, out);
}